// Round 9
// baseline (252.619 us; speedup 1.0000x reference)
//
#include <hip/hip_runtime.h>
#include <hip/hip_cooperative_groups.h>
#include <math.h>

namespace cg = cooperative_groups;

#define NA   21
#define NM   64
#define ND   210
#define DP   224            // padded descriptor row
#define NT   8192
#define NCH  28             // 8-wide k-chunks per descriptor row (224/8)

#define QC 0.22360679774997896f   // sqrt(5)/10
#define KE 0.016666666666666666f  // 5/(3*sig^2)

typedef short bf8 __attribute__((ext_vector_type(8)));   // 8 bf16 (4 VGPRs)
typedef float f4  __attribute__((ext_vector_type(4)));   // 4 fp32 acc
typedef _Float16 h4 __attribute__((ext_vector_type(4))); // 8-B fp16 vector

// ---- workspace layout (float offsets) ----
// Af  : stage1 A frags [mtile 4][kq 28][col_m 16][8 d]  (bf16)
// qxsG: fp32 [56][64][4]
// Pbuf: fp16 [m 64][b 256][d 224] partials (w1·X^T + e1·J^T per 32-t slice)
// EsPart/WaPart: [m 64][slot 512] fp32  (slot = b*2 + sub)
#define O_AF   0u          // 7168 floats (14336 shorts)
#define O_QG   7168u       // 14336 floats
#define O_NX   21504u      // 64
#define O_ESP  21568u      // 32768
#define O_WAP  54336u      // 32768
#define O_PB   87104u      // 3670016 halfs

__device__ __forceinline__ unsigned short f2bf(float f) {
    unsigned u = __float_as_uint(f);
    u += 0x7fffu + ((u >> 16) & 1u);
    return (unsigned short)(u >> 16);
}
__device__ __forceinline__ float bf2f(unsigned short h) {
    return __uint_as_float((unsigned)h << 16);
}

__device__ __forceinline__ void d_to_ij(int d, int& i, int& j) {
    int ii = (int)((1.0f + sqrtf(1.0f + 8.0f * (float)d)) * 0.5f);
    while (ii * (ii - 1) / 2 > d) --ii;
    while ((ii + 1) * ii / 2 <= d) ++ii;
    i = ii;
    j = d - ii * (ii - 1) / 2;
}

// Single cooperative kernel: 256 blocks x 512 threads (1 block/CU).
// Phase G (blocks<64): geometry -> Af/qxsG/nx.   grid.sync
// Phase S (all): fused prep + stage-1 + stage-2 -> EsPart/WaPart/Pbuf. grid.sync
// Phase F (blocks<64): reductions + expand_tril + forces + Es -> out.
// Phase G/F scratch aliases the xJh LDS region (static LDS total 37.4 KB).
__global__ __launch_bounds__(512) void k_all(
    const float* __restrict__ xs, const float* __restrict__ Jx,
    const float* __restrict__ Rs,
    unsigned short* __restrict__ Af, float* __restrict__ qxsG,
    float* __restrict__ nxg,
    float* __restrict__ EsPart, float* __restrict__ WaPart,
    _Float16* __restrict__ Pbuf, float* __restrict__ out) {
    const int b = blockIdx.x, tid = threadIdx.x;
    const int lane = tid & 63;
    const int wave = tid >> 6;
    const int mtile = wave & 3, sub = wave >> 2;
    const int col = lane & 15, quad = lane >> 4;

    __shared__ __align__(16) unsigned short xJh[2 * 32 * DP];  // 28672 B
    __shared__ unsigned short Dwh[64][33];                     // 4224 B
    __shared__ unsigned short Deh[64][33];                     // 4224 B
    __shared__ float ntL[32], cjL[32];
    char* xB = (char*)xJh;

    // ================= phase G: geometry (blocks 0..63, m = b) =============
    if (b < NM) {
        float* Rg  = (float*)xB;            // 252 B
        float* red = (float*)(xB + 256);    // 1024 B
        if (tid < NA * 3) Rg[tid] = Rs[b * NA * 3 + tid];
        __syncthreads();
        float local = 0.0f;
        if (tid < DP) {
            float vr = 0.0f;
            unsigned short hv = 0;
            if (tid < ND) {
                int i, j; d_to_ij(tid, i, j);
                float dx = Rg[i * 3] - Rg[j * 3];
                float dy = Rg[i * 3 + 1] - Rg[j * 3 + 1];
                float dz = Rg[i * 3 + 2] - Rg[j * 3 + 2];
                float v = QC / sqrtf(dx * dx + dy * dy + dz * dz);
                hv = f2bf(v);
                vr = bf2f(hv);
            }
            Af[(((b >> 4) * NCH + (tid >> 3)) * 16 + (b & 15)) * 8 + (tid & 7)] = hv;
            qxsG[(tid >> 2) * 256 + b * 4 + (tid & 3)] = vr;
            local = vr * vr;
        }
        if (tid < 256) red[tid] = local;
        __syncthreads();
        for (int s = 128; s > 0; s >>= 1) {
            if (tid < s) red[tid] += red[tid + s];
            __syncthreads();
        }
        if (tid == 0) nxg[b] = red[0];
    }
    __threadfence();
    cg::this_grid().sync();

    // ================= phase S: prep + stage-1 + stage-2 (all blocks) =======
    {
        // A-panel + nx (produced in phase G, device-visible after grid sync)
        const unsigned short* ap = Af + ((size_t)(mtile * NCH + quad) * 16 + col) * 8;
        bf8 af[7];
#pragma unroll
        for (int kc = 0; kc < 7; ++kc) af[kc] = *(const bf8*)(ap + kc * 512);
        float nxv[4];
#pragma unroll
        for (int r = 0; r < 4; ++r) nxv[r] = nxg[mtile * 16 + quad * 4 + r];

        // zero the d-pad [210,224): 2 arrays x 32 rows x 7 dwords
        if (tid < 448) {
            const int arr = tid / 224, rem = tid - arr * 224;
            const int t = rem / 7, k2 = rem - t * 7;
            *(unsigned*)(xB + arr * 14336 +
                         (((unsigned)(t * 448 + 420 + k2 * 4)) ^ ((unsigned)((t & 7) << 4)))) = 0u;
        }
        // load+convert: 3360 float2 per array; byte = 4p + 28t, swz ((t&7)<<4)
        const float2* sx = (const float2*)(xs + (size_t)b * 32 * ND);
        const float2* sj = (const float2*)(Jx + (size_t)b * 32 * ND);
#pragma unroll
        for (int k = 0; k < 7; ++k) {
            const int p = k * 512 + tid;
            if (p < 3360) {
                const float2 vx = sx[p];
                const float2 vj = sj[p];
                const int t = p / 105;
                const unsigned bo = ((unsigned)(4 * p + 28 * t)) ^ ((unsigned)((t & 7) << 4));
                *(unsigned*)(xB + bo) =
                    (unsigned)f2bf(QC * vx.x) | ((unsigned)f2bf(QC * vx.y) << 16);
                *(unsigned*)(xB + 14336 + bo) =
                    (unsigned)f2bf(vj.x) | ((unsigned)f2bf(vj.y) << 16);
            }
        }
        __syncthreads();

        // stage-1 MFMA: A in regs, B from swizzled LDS; this wave's 16-t half
        const unsigned base0 = (unsigned)((sub * 16 + col) * 448 + quad * 16);
        const unsigned swc = (unsigned)((col & 7) << 4);
        bf8 bx[2], bj[2];
        bx[0] = *(const bf8*)(xB + (base0 ^ swc));
        bj[0] = *(const bf8*)(xB + 14336 + (base0 ^ swc));
        bx[1] = *(const bf8*)(xB + ((base0 + 64) ^ swc));
        bj[1] = *(const bf8*)(xB + 14336 + ((base0 + 64) ^ swc));
        f4 c1 = {0.f, 0.f, 0.f, 0.f};
        f4 c2 = {0.f, 0.f, 0.f, 0.f};
#pragma unroll
        for (int kc = 0; kc < 7; ++kc) {
            const int s = kc & 1;
            c1 = __builtin_amdgcn_mfma_f32_16x16x32_bf16(af[kc], bx[s], c1, 0, 0, 0);
            c2 = __builtin_amdgcn_mfma_f32_16x16x32_bf16(af[kc], bj[s], c2, 0, 0, 0);
            if (kc < 5) {
                bx[s] = *(const bf8*)(xB + ((base0 + (kc + 2) * 64) ^ swc));
                bj[s] = *(const bf8*)(xB + 14336 + ((base0 + (kc + 2) * 64) ^ swc));
            }
        }

        // rowstats in the MFMA shadow (32 rows; pads zero -> exact)
        {
            const int tt = tid >> 4, l = tid & 15;
            const unsigned swt = (unsigned)((tt & 7) << 4);
            float sn = 0.0f, sc2 = 0.0f;
#pragma unroll
            for (int c = l; c < DP; c += 16) {
                const unsigned off = ((unsigned)(tt * 448 + 2 * c)) ^ swt;
                const float x = bf2f(*(const unsigned short*)(xB + off));
                const float jv = bf2f(*(const unsigned short*)(xB + 14336 + off));
                sn = fmaf(x, x, sn);
                sc2 = fmaf(x, jv, sc2);
            }
#pragma unroll
            for (int o = 1; o < 16; o <<= 1) {
                sn += __shfl_xor(sn, o);
                sc2 += __shfl_xor(sc2, o);
            }
            if (l == 0) { ntL[tt] = sn; cjL[tt] = sc2; }
        }
        __syncthreads();

        // epilogue: lane holds D[m=mtile*16+quad*4+r][t=b*32+sub*16+col]
        const int tloc = sub * 16 + col;
        const float ntv = ntL[tloc], cjv = cjL[tloc];
        float esA[4], wlA[4];
#pragma unroll
        for (int r = 0; r < 4; ++r) {
            const int m = mtile * 16 + quad * 4 + r;
            float sq = fmaxf(nxv[r] - 2.0f * c1[r] + ntv, 0.0f);
            float xd = sqrtf(sq);
            float e = KE * expf(-xd);
            float dotv = c2[r] - cjv;
            float wv = e * dotv;
            float ev = e * (1.0f + xd);
            Dwh[m][tloc] = f2bf(wv);
            Deh[m][tloc] = f2bf(ev);
            esA[r] = ev * dotv;
            wlA[r] = wv;
        }
        // Es/Wa partials (register-only + shfl; global store)
#pragma unroll
        for (int r = 0; r < 4; ++r) {
            float e = esA[r], wl = wlA[r];
#pragma unroll
            for (int o = 1; o < 16; o <<= 1) {
                e += __shfl_xor(e, o);
                wl += __shfl_xor(wl, o);
            }
            if (col == 0) {
                const int m = mtile * 16 + quad * 4 + r;
                EsPart[(size_t)m * 512 + b * 2 + sub] = e;
                WaPart[(size_t)m * 512 + b * 2 + sub] = wl;
            }
        }
        __syncthreads();

        // fused stage-2: P_b[m][d] = w1_b·X_b^T + e1_b·J_b^T  (K = 32 t)
        union { unsigned short us[8]; bf8 v; } uaw, uae;
#pragma unroll
        for (int i = 0; i < 8; ++i) {
            uaw.us[i] = Dwh[mtile * 16 + col][quad * 8 + i];
            uae.us[i] = Deh[mtile * 16 + col][quad * 8 + i];
        }
        const int dt0 = sub * 7;
#pragma unroll
        for (int dd = 0; dd < 7; ++dd) {
            const int dt = dt0 + dd;
            union { unsigned short us[8]; bf8 v; } ubx, ubj;
#pragma unroll
            for (int i = 0; i < 8; ++i) {
                const int t = quad * 8 + i;
                const unsigned off =
                    ((unsigned)(t * 448 + 2 * (dt * 16 + col))) ^ ((unsigned)((t & 7) << 4));
                ubx.us[i] = *(const unsigned short*)(xB + off);
                ubj.us[i] = *(const unsigned short*)(xB + 14336 + off);
            }
            f4 z = {0.f, 0.f, 0.f, 0.f};
            f4 dA = __builtin_amdgcn_mfma_f32_16x16x32_bf16(uaw.v, ubx.v, z, 0, 0, 0);
            f4 dB = __builtin_amdgcn_mfma_f32_16x16x32_bf16(uae.v, ubj.v, z, 0, 0, 0);
#pragma unroll
            for (int r = 0; r < 4; ++r) {
                const int m = mtile * 16 + quad * 4 + r;
                Pbuf[((size_t)(m * 256 + b)) * DP + dt * 16 + col] =
                    (_Float16)(dA[r] + dB[r]);
            }
        }
    }
    __threadfence();
    cg::this_grid().sync();

    // ================= phase F: finish (blocks 0..63, m = b) ================
    if (b < NM) {
        const int m = b;
        float* Rf   = (float*)xB;                      // 252 B
        float (*Ff)[NA] = (float(*)[NA])(xB + 256);    // 1764 B
        float* redE = (float*)(xB + 2048);             // 1024 B
        float* redW = (float*)(xB + 3072);             // 1024 B
        float (*ABp)[DP] = (float(*)[DP])(xB + 4096);  // 8*224*4 = 7168 B
        if (tid < NA * 3) Rf[tid] = Rs[m * NA * 3 + tid];
        if (tid < NA) Ff[tid][tid] = 0.0f;
        {   // b-reduction: 8 wave groups x 32-deep half4 coalesced chains
            const int g = tid >> 6, l = tid & 63;
            const int d0 = l * 4;
            if (d0 < DP) {
                const _Float16* p0 = Pbuf + (size_t)m * 256 * DP + (size_t)g * 32 * DP + d0;
                float s0 = 0.0f, s1 = 0.0f, s2 = 0.0f, s3 = 0.0f;
#pragma unroll
                for (int bb = 0; bb < 32; ++bb) {
                    const h4 v = *(const h4*)(p0 + bb * DP);
                    s0 += (float)v[0];
                    s1 += (float)v[1];
                    s2 += (float)v[2];
                    s3 += (float)v[3];
                }
                ABp[g][d0] = s0;
                ABp[g][d0 + 1] = s1;
                ABp[g][d0 + 2] = s2;
                ABp[g][d0 + 3] = s3;
            }
        }
        if (tid < 256) {   // contiguous per-m Es/Wa partials
            const float2 ep = ((const float2*)(EsPart + (size_t)m * 512))[tid];
            const float2 wp = ((const float2*)(WaPart + (size_t)m * 512))[tid];
            redE[tid] = ep.x + ep.y;
            redW[tid] = wp.x + wp.y;
        }
        __syncthreads();
        for (int s = 128; s > 0; s >>= 1) {
            if (tid < s) {
                redE[tid] += redE[tid + s];
                redW[tid] += redW[tid + s];
            }
            __syncthreads();
        }
        const float Wa = redW[0];
        if (tid < ND) {
            int i, j; d_to_ij(tid, i, j);
            float dx = Rf[i * 3] - Rf[j * 3];
            float dy = Rf[i * 3 + 1] - Rf[j * 3 + 1];
            float dz = Rf[i * 3 + 2] - Rf[j * 3 + 2];
            float dist2 = dx * dx + dy * dy + dz * dz;
            float ab = 0.0f;
#pragma unroll
            for (int g = 0; g < 8; ++g) ab += ABp[g][tid];
            float fsx = qxsG[(tid >> 2) * 256 + m * 4 + (tid & 3)] * Wa - ab;
            float f = fsx / (dist2 * sqrtf(dist2));
            Ff[i][j] = f;
            Ff[j][i] = f;
        }
        __syncthreads();
        if (tid < NA * 3) {
            int a = tid / 3, c = tid % 3;
            float s = 0.0f;
            for (int bb2 = 0; bb2 < NA; ++bb2) {
                if (bb2 == a) continue;
                s += Ff[a][bb2] * (Rf[a * 3 + c] - Rf[bb2 * 3 + c]);
            }
            out[NM + m * NA * 3 + tid] = s;
        }
        if (tid == 0) out[m] = redE[0] / QC;
    }
}

extern "C" void kernel_launch(void* const* d_in, const int* in_sizes, int n_in,
                              void* d_out, int out_size, void* d_ws, size_t ws_size,
                              hipStream_t stream) {
    const float* Rs = (const float*)d_in[0];
    const float* xs_train = (const float*)d_in[1];
    const float* Jx_alphas = (const float*)d_in[2];
    float* out = (float*)d_out;
    float* ws = (float*)d_ws;

    unsigned short* Af = (unsigned short*)(ws + O_AF);
    float* qxsG   = ws + O_QG;
    float* nx     = ws + O_NX;
    float* EsPart = ws + O_ESP;
    float* WaPart = ws + O_WAP;
    _Float16* Pbuf = (_Float16*)(ws + O_PB);

    void* args[] = {(void*)&xs_train, (void*)&Jx_alphas, (void*)&Rs,
                    (void*)&Af, (void*)&qxsG, (void*)&nx,
                    (void*)&EsPart, (void*)&WaPart, (void*)&Pbuf, (void*)&out};
    hipLaunchCooperativeKernel((const void*)k_all, dim3(256), dim3(512),
                               args, 0, stream);
}

// Round 10
// 83.770 us; speedup vs baseline: 3.0156x; 3.0156x over previous
//
#include <hip/hip_runtime.h>
#include <math.h>

#define NA   21
#define NM   64
#define ND   210
#define DP   224            // padded descriptor row
#define NT   8192
#define NCH  28             // 8-wide k-chunks per descriptor row (224/8)

#define QC 0.22360679774997896f   // sqrt(5)/10
#define KE 0.016666666666666666f  // 5/(3*sig^2)

typedef short bf8 __attribute__((ext_vector_type(8)));   // 8 bf16 (4 VGPRs)
typedef float f4  __attribute__((ext_vector_type(4)));   // 4 fp32 acc

// ---- workspace layout (float offsets) ----
// Af  : stage1 A frags [mtile 4][kq 28][col_m 16][8 d]  (bf16)
// qxsG: fp32 [56][64][4]
// Pbuf: fp16 [m 64][b 256][d 224] partials (w1·X^T + e1·J^T per 32-t slice)
// EsPart/WaPart: [m 64][slot 512] fp32  (slot = b*2 + sub)
#define O_AF   0u          // 7168 floats (14336 shorts)
#define O_QG   7168u       // 14336 floats
#define O_NX   21504u      // 64
#define O_ESP  21568u      // 32768
#define O_WAP  54336u      // 32768
#define O_PB   87104u      // 3670016 halfs

__device__ __forceinline__ unsigned short f2bf(float f) {
    unsigned u = __float_as_uint(f);
    u += 0x7fffu + ((u >> 16) & 1u);
    return (unsigned short)(u >> 16);
}
__device__ __forceinline__ float bf2f(unsigned short h) {
    return __uint_as_float((unsigned)h << 16);
}

__device__ __forceinline__ void d_to_ij(int d, int& i, int& j) {
    int ii = (int)((1.0f + sqrtf(1.0f + 8.0f * (float)d)) * 0.5f);
    while (ii * (ii - 1) / 2 > d) --ii;
    while ((ii + 1) * ii / 2 <= d) ++ii;
    i = ii;
    j = d - ii * (ii - 1) / 2;
}

// Tiny geometry prep: per-molecule descriptors -> Af frags, qxsG, nx.
__global__ __launch_bounds__(256) void k_geom(
    const float* __restrict__ Rs, unsigned short* __restrict__ Af,
    float* __restrict__ qxsG, float* __restrict__ nx) {
    const int m = blockIdx.x, tid = threadIdx.x;
    __shared__ float R[NA * 3];
    __shared__ float red[256];
    if (tid < NA * 3) R[tid] = Rs[m * NA * 3 + tid];
    __syncthreads();
    float local = 0.0f;
    if (tid < DP) {
        float vr = 0.0f;
        unsigned short hv = 0;
        if (tid < ND) {
            int i, j; d_to_ij(tid, i, j);
            float dx = R[i * 3] - R[j * 3];
            float dy = R[i * 3 + 1] - R[j * 3 + 1];
            float dz = R[i * 3 + 2] - R[j * 3 + 2];
            float v = QC / sqrtf(dx * dx + dy * dy + dz * dz);
            hv = f2bf(v);
            vr = bf2f(hv);
        }
        Af[(((m >> 4) * NCH + (tid >> 3)) * 16 + (m & 15)) * 8 + (tid & 7)] = hv;
        qxsG[(tid >> 2) * 256 + m * 4 + (tid & 3)] = vr;
        local = vr * vr;
    }
    red[tid] = local;
    __syncthreads();
    for (int s = 128; s > 0; s >>= 1) {
        if (tid < s) red[tid] += red[tid + s];
        __syncthreads();
    }
    if (tid == 0) nx[m] = red[0];
}

// Fused prep + stage-1 + stage-2. Grid 256 x 512 threads: block b owns t-rows
// [b*32, b*32+32). 8 waves: wave = (sub<<2)|mtile; sub picks the 16-t half for
// stage-1, the 7-dt half for stage-2.
// xs/Jx read ONCE -> bf16 swizzled LDS image; stage-1 MFMA + rowstats off it;
// epilogue leaves w1/e1 as a bf16 LDS tile; stage-2 (K=32 over this block's
// 32 t) multiplies them against the transposed image IN LDS and writes fp16
// partials straight to Pbuf. No frag arrays ever touch global memory.
__global__ __launch_bounds__(512) void k_s1p2(
    const float* __restrict__ xs, const float* __restrict__ Jx,
    const unsigned short* __restrict__ Af, const float* __restrict__ nxg,
    float* __restrict__ EsPart, float* __restrict__ WaPart,
    _Float16* __restrict__ Pbuf) {
    const int b = blockIdx.x, tid = threadIdx.x;
    const int lane = tid & 63;
    const int wave = tid >> 6;
    const int mtile = wave & 3, sub = wave >> 2;
    const int col = lane & 15, quad = lane >> 4;

    __shared__ unsigned short xJh[2 * 32 * DP];   // 28672 B, rows XOR-swizzled
    __shared__ unsigned short Dwh[64][33];        // w1 bf16 [m][t-local]
    __shared__ unsigned short Deh[64][33];        // e1 bf16
    __shared__ float ntL[32], cjL[32];
    char* xB = (char*)xJh;

    // A-panel (L2-hot) + nx issued early, held through the prep phase
    const unsigned short* ap = Af + ((size_t)(mtile * NCH + quad) * 16 + col) * 8;
    bf8 af[7];
#pragma unroll
    for (int kc = 0; kc < 7; ++kc) af[kc] = *(const bf8*)(ap + kc * 512);
    float nxv[4];
#pragma unroll
    for (int r = 0; r < 4; ++r) nxv[r] = nxg[mtile * 16 + quad * 4 + r];

    // zero the d-pad [210,224): 2 arrays x 32 rows x 7 dwords
    if (tid < 448) {
        const int arr = tid / 224, rem = tid - arr * 224;
        const int t = rem / 7, k2 = rem - t * 7;
        *(unsigned*)(xB + arr * 14336 +
                     (((unsigned)(t * 448 + 420 + k2 * 4)) ^ ((unsigned)((t & 7) << 4)))) = 0u;
    }
    // load+convert: 3360 float2 per array; row = p/105 (210 even -> pairs never
    // cross rows); byte = t*448 + 2d = 4p + 28t, swizzled by ((t&7)<<4)
    const float2* sx = (const float2*)(xs + (size_t)b * 32 * ND);
    const float2* sj = (const float2*)(Jx + (size_t)b * 32 * ND);
#pragma unroll
    for (int k = 0; k < 7; ++k) {
        const int p = k * 512 + tid;
        if (p < 3360) {
            const float2 vx = sx[p];
            const float2 vj = sj[p];
            const int t = p / 105;
            const unsigned bo = ((unsigned)(4 * p + 28 * t)) ^ ((unsigned)((t & 7) << 4));
            *(unsigned*)(xB + bo) =
                (unsigned)f2bf(QC * vx.x) | ((unsigned)f2bf(QC * vx.y) << 16);
            *(unsigned*)(xB + 14336 + bo) =
                (unsigned)f2bf(vj.x) | ((unsigned)f2bf(vj.y) << 16);
        }
    }
    __syncthreads();

    // ---- stage-1 MFMA: A in regs, B from swizzled LDS; this wave's 16-t half
    const unsigned base0 = (unsigned)((sub * 16 + col) * 448 + quad * 16);
    const unsigned swc = (unsigned)((col & 7) << 4);
    bf8 bx[2], bj[2];
    bx[0] = *(const bf8*)(xB + (base0 ^ swc));
    bj[0] = *(const bf8*)(xB + 14336 + (base0 ^ swc));
    bx[1] = *(const bf8*)(xB + ((base0 + 64) ^ swc));
    bj[1] = *(const bf8*)(xB + 14336 + ((base0 + 64) ^ swc));
    f4 c1 = {0.f, 0.f, 0.f, 0.f};
    f4 c2 = {0.f, 0.f, 0.f, 0.f};
#pragma unroll
    for (int kc = 0; kc < 7; ++kc) {
        const int s = kc & 1;
        c1 = __builtin_amdgcn_mfma_f32_16x16x32_bf16(af[kc], bx[s], c1, 0, 0, 0);
        c2 = __builtin_amdgcn_mfma_f32_16x16x32_bf16(af[kc], bj[s], c2, 0, 0, 0);
        if (kc < 5) {
            bx[s] = *(const bf8*)(xB + ((base0 + (kc + 2) * 64) ^ swc));
            bj[s] = *(const bf8*)(xB + 14336 + ((base0 + (kc + 2) * 64) ^ swc));
        }
    }

    // ---- rowstats in the MFMA shadow (32 rows; pads are zero -> exact)
    {
        const int tt = tid >> 4, l = tid & 15;
        const unsigned swt = (unsigned)((tt & 7) << 4);
        float sn = 0.0f, sc2 = 0.0f;
#pragma unroll
        for (int c = l; c < DP; c += 16) {
            const unsigned off = ((unsigned)(tt * 448 + 2 * c)) ^ swt;
            const float x = bf2f(*(const unsigned short*)(xB + off));
            const float jv = bf2f(*(const unsigned short*)(xB + 14336 + off));
            sn = fmaf(x, x, sn);
            sc2 = fmaf(x, jv, sc2);
        }
#pragma unroll
        for (int o = 1; o < 16; o <<= 1) {
            sn += __shfl_xor(sn, o);
            sc2 += __shfl_xor(sc2, o);
        }
        if (l == 0) { ntL[tt] = sn; cjL[tt] = sc2; }
    }
    __syncthreads();

    // ---- epilogue: lane holds D[m=mtile*16+quad*4+r][t=b*32+sub*16+col]
    const int tloc = sub * 16 + col;
    const float ntv = ntL[tloc], cjv = cjL[tloc];
    float esA[4], wlA[4];
#pragma unroll
    for (int r = 0; r < 4; ++r) {
        const int m = mtile * 16 + quad * 4 + r;
        float sq = fmaxf(nxv[r] - 2.0f * c1[r] + ntv, 0.0f);
        float xd = sqrtf(sq);
        float e = KE * expf(-xd);
        float dotv = c2[r] - cjv;
        float wv = e * dotv;
        float ev = e * (1.0f + xd);
        Dwh[m][tloc] = f2bf(wv);
        Deh[m][tloc] = f2bf(ev);
        esA[r] = ev * dotv;
        wlA[r] = wv;
    }
    // Es/Wa partials (register-only + shfl; global store, no LDS dependence)
#pragma unroll
    for (int r = 0; r < 4; ++r) {
        float e = esA[r], wl = wlA[r];
#pragma unroll
        for (int o = 1; o < 16; o <<= 1) {
            e += __shfl_xor(e, o);
            wl += __shfl_xor(wl, o);
        }
        if (col == 0) {
            const int m = mtile * 16 + quad * 4 + r;
            EsPart[(size_t)m * 512 + b * 2 + sub] = e;
            WaPart[(size_t)m * 512 + b * 2 + sub] = wl;
        }
    }
    __syncthreads();

    // ---- fused stage-2: P_b[m][d] = w1_b·X_b^T + e1_b·J_b^T  (K = 32 t)
    // A frags: lane (col,quad) holds A[m=mtile*16+col][k=quad*8+i]
    union { unsigned short us[8]; bf8 v; } uaw, uae;
#pragma unroll
    for (int i = 0; i < 8; ++i) {
        uaw.us[i] = Dwh[mtile * 16 + col][quad * 8 + i];
        uae.us[i] = Deh[mtile * 16 + col][quad * 8 + i];
    }
    const int dt0 = sub * 7;
#pragma unroll
    for (int dd = 0; dd < 7; ++dd) {
        const int dt = dt0 + dd;
        // B frags: lane holds B[k=t=quad*8+i][n=d=dt*16+col] from the image
        union { unsigned short us[8]; bf8 v; } ubx, ubj;
#pragma unroll
        for (int i = 0; i < 8; ++i) {
            const int t = quad * 8 + i;
            const unsigned off =
                ((unsigned)(t * 448 + 2 * (dt * 16 + col))) ^ ((unsigned)((t & 7) << 4));
            ubx.us[i] = *(const unsigned short*)(xB + off);
            ubj.us[i] = *(const unsigned short*)(xB + 14336 + off);
        }
        f4 z = {0.f, 0.f, 0.f, 0.f};
        f4 dA = __builtin_amdgcn_mfma_f32_16x16x32_bf16(uaw.v, ubx.v, z, 0, 0, 0);
        f4 dB = __builtin_amdgcn_mfma_f32_16x16x32_bf16(uae.v, ubj.v, z, 0, 0, 0);
        // lane holds D[m=mtile*16+quad*4+r][d=dt*16+col]
#pragma unroll
        for (int r = 0; r < 4; ++r) {
            const int m = mtile * 16 + quad * 4 + r;
            Pbuf[((size_t)(m * 256 + b)) * DP + dt * 16 + col] =
                (_Float16)(dA[r] + dB[r]);
        }
    }
}

// grid 64 (m) x 512: Pbuf reduction split into two 128-deep halves (one per
// tid>>8 group, combined via LDS) + Es/Wa partial reduce + expand_tril +
// force contraction + Es
__global__ __launch_bounds__(512) void k_final(
    const float* __restrict__ Rs, const float* __restrict__ qxsG,
    const _Float16* __restrict__ Pbuf, const float* __restrict__ EsPart,
    const float* __restrict__ WaPart, float* __restrict__ out) {
    int m = blockIdx.x, tid = threadIdx.x;
    __shared__ float R[NA * 3];
    __shared__ float Ff[NA][NA];
    __shared__ float redE[256];
    __shared__ float redW[256];
    __shared__ float ABp[2][DP];
    if (tid < NA * 3) R[tid] = Rs[m * NA * 3 + tid];
    if (tid < NA) Ff[tid][tid] = 0.0f;
    {   // b-reduction: half h covers bb in [h*128, h*128+128), coalesced rows
        const int h = tid >> 8, td = tid & 255;
        if (td < DP) {
            const _Float16* p0 = Pbuf + (size_t)m * 256 * DP + (size_t)h * 128 * DP + td;
            float s0 = 0.0f, s1 = 0.0f, s2 = 0.0f, s3 = 0.0f;
#pragma unroll
            for (int bb = 0; bb < 128; bb += 4) {
                s0 += (float)p0[(bb + 0) * DP];
                s1 += (float)p0[(bb + 1) * DP];
                s2 += (float)p0[(bb + 2) * DP];
                s3 += (float)p0[(bb + 3) * DP];
            }
            ABp[h][td] = (s0 + s1) + (s2 + s3);
        }
    }
    if (tid < 256) {   // contiguous per-m Es/Wa partials
        const float2 ep = ((const float2*)(EsPart + (size_t)m * 512))[tid];
        const float2 wp = ((const float2*)(WaPart + (size_t)m * 512))[tid];
        redE[tid] = ep.x + ep.y;
        redW[tid] = wp.x + wp.y;
    }
    __syncthreads();
    for (int s = 128; s > 0; s >>= 1) {
        if (tid < s) {
            redE[tid] += redE[tid + s];
            redW[tid] += redW[tid + s];
        }
        __syncthreads();
    }
    const float Wa = redW[0];
    if (tid < ND) {
        int i, j; d_to_ij(tid, i, j);
        float dx = R[i * 3] - R[j * 3];
        float dy = R[i * 3 + 1] - R[j * 3 + 1];
        float dz = R[i * 3 + 2] - R[j * 3 + 2];
        float dist2 = dx * dx + dy * dy + dz * dz;
        float ab = ABp[0][tid] + ABp[1][tid];
        float fsx = qxsG[(tid >> 2) * 256 + m * 4 + (tid & 3)] * Wa - ab;
        float f = fsx / (dist2 * sqrtf(dist2));
        Ff[i][j] = f;
        Ff[j][i] = f;
    }
    __syncthreads();
    if (tid < NA * 3) {
        int a = tid / 3, c = tid % 3;
        float s = 0.0f;
        for (int b = 0; b < NA; ++b) {
            if (b == a) continue;
            s += Ff[a][b] * (R[a * 3 + c] - R[b * 3 + c]);
        }
        out[NM + m * NA * 3 + tid] = s;
    }
    if (tid == 0) out[m] = redE[0] / QC;
}

extern "C" void kernel_launch(void* const* d_in, const int* in_sizes, int n_in,
                              void* d_out, int out_size, void* d_ws, size_t ws_size,
                              hipStream_t stream) {
    const float* Rs = (const float*)d_in[0];
    const float* xs_train = (const float*)d_in[1];
    const float* Jx_alphas = (const float*)d_in[2];
    float* out = (float*)d_out;
    float* ws = (float*)d_ws;

    unsigned short* Af = (unsigned short*)(ws + O_AF);
    float* qxsG   = ws + O_QG;
    float* nx     = ws + O_NX;
    float* EsPart = ws + O_ESP;
    float* WaPart = ws + O_WAP;
    _Float16* Pbuf = (_Float16*)(ws + O_PB);

    k_geom<<<NM, 256, 0, stream>>>(Rs, Af, qxsG, nx);
    k_s1p2<<<256, 512, 0, stream>>>(xs_train, Jx_alphas, Af, nx,
                                    EsPart, WaPart, Pbuf);
    k_final<<<NM, 512, 0, stream>>>(Rs, qxsG, Pbuf, EsPart, WaPart, out);
}